// Round 1
// baseline (161.554 us; speedup 1.0000x reference)
//
#include <hip/hip_runtime.h>
#include <math.h>

#define kNB 16
#define kNA 5
#define kNH 128
#define kNW 128
#define kMaxT 50
#define kNC 20
#define kCH 26
#define kRowW 33
#define kNTot (kNB*kNA*kNH*kNW)   // 1,310,720

// ws layout (doubles):
// 0 S_all (sum softplus(conf) over all cells)
// 1 nProposals
// 2 S_excl (sum softplus over excluded cells: mask==1 || conf_mask==0)
// 3 cnt_excl
// 4 nM count (sum mask)
// 5 bce_mask (sum softplus(p)-p over masked)
// 6 sx, 7 sy, 8 sw, 9 sh  (masked squared errors)
// 10 ce_sum
// 11 nGT, 12 nCorrect

__device__ __forceinline__ float softplusf(float x) {
    return fmaxf(x, 0.0f) + log1pf(expf(-fabsf(x)));
}

__device__ __forceinline__ double wave_sum(double v) {
    #pragma unroll
    for (int off = 32; off > 0; off >>= 1) v += __shfl_down(v, off, 64);
    return v;
}

__device__ __forceinline__ float inv_tanhf(float y) {
    float yc = fminf(fmaxf(y, -1.0f + 1e-6f), 1.0f - 1e-6f);
    float v = 0.5f * logf((1.0f + yc) / (1.0f - yc));
    return (y <= -1.0f) ? -2.0f : ((y >= 1.0f) ? 2.0f : v);
}

extern "C" __global__ __launch_bounds__(256)
void yolo_dense_conf(const float* __restrict__ pred, double* __restrict__ ws) {
    int tid = blockIdx.x * blockDim.x + threadIdx.x;
    int stride = gridDim.x * blockDim.x;
    float sp_sum = 0.0f;
    unsigned int prop = 0;
    for (long long c = tid; c < kNTot; c += stride) {
        float p = pred[c * kCH];
        sp_sum += softplusf(p);
        prop += (p > 0.0f) ? 1u : 0u;
    }
    __shared__ double s_sp[256];
    __shared__ unsigned int s_pr[256];
    s_sp[threadIdx.x] = (double)sp_sum;
    s_pr[threadIdx.x] = prop;
    __syncthreads();
    for (int off = 128; off > 0; off >>= 1) {
        if ((int)threadIdx.x < off) {
            s_sp[threadIdx.x] += s_sp[threadIdx.x + off];
            s_pr[threadIdx.x] += s_pr[threadIdx.x + off];
        }
        __syncthreads();
    }
    if (threadIdx.x == 0) {
        atomicAdd(&ws[0], s_sp[0]);
        atomicAdd(&ws[1], (double)s_pr[0]);
    }
}

extern "C" __global__ __launch_bounds__(64)
void yolo_targets(const float* __restrict__ pred, const float* __restrict__ target,
                  const int* __restrict__ tsizes, const float* __restrict__ anchors,
                  double* __restrict__ ws) {
    const int b = blockIdx.x;
    const int tid = threadIdx.x;

    __shared__ float s_t[kMaxT][kRowW];
    __shared__ float s_aw[kNA], s_ah[kNA];
    // per-target phase-2 results
    __shared__ int s_cell[kMaxT], s_bn[kMaxT], s_zm[kMaxT], s_valid[kMaxT];
    __shared__ int s_label[kMaxT], s_corr[kMaxT];
    __shared__ float s_tx[kMaxT], s_ty[kMaxT], s_tw[kMaxT], s_th[kMaxT];
    // serialized final state
    __shared__ int s_cl[kMaxT];          // distinct cell ids
    __shared__ int s_cm[kMaxT];          // conf_mask bits per anchor (1 = conf_mask==1)
    __shared__ int s_mk[kMaxT];          // mask bits per anchor
    __shared__ float s_v[kMaxT][kNA][4]; // tx,ty,tw,th at masked (cell,anchor)
    __shared__ int s_vl[kMaxT][kNA];     // label at masked (cell,anchor)
    __shared__ int s_ncell;

    // phase 1: stage this batch's targets + anchors
    for (int i = tid; i < kMaxT * kRowW; i += 64)
        ((float*)s_t)[i] = target[(long long)b * kMaxT * kRowW + i];
    if (tid < kNA) {
        s_aw[tid] = anchors[tid * 2 + 0] / 8.0f;
        s_ah[tid] = anchors[tid * 2 + 1] / 8.0f;
    }
    __syncthreads();

    const int tsz = tsizes[b];

    // phase 2: per-target independent compute (parallel across 50 lanes)
    if (tid < kMaxT) {
        const int t = tid;
        const float* row = s_t[t];
        float gx = row[0] / 8.0f, gy = row[1] / 8.0f;
        float gh = row[3] / 8.0f, gw = row[4] / 8.0f;
        int valid = (t < tsz) && (gw != 0.0f) && (gh != 0.0f);
        int gi = (int)gx; gi = min(max(gi, 0), kNW - 1);
        int gj = (int)gy; gj = min(max(gj, 0), kNH - 1);

        float best = -1.0f; int bn = 0; int zm = 0;
        #pragma unroll
        for (int a = 0; a < kNA; ++a) {
            float aw = s_aw[a], ah = s_ah[a];
            float inter = fmaxf(fminf(gw, aw) + 1.0f, 0.0f) * fmaxf(fminf(gh, ah) + 1.0f, 0.0f);
            float iou = inter / ((gw + 1.0f) * (gh + 1.0f) + (aw + 1.0f) * (ah + 1.0f) - inter + 1e-16f);
            if (iou > best) { best = iou; bn = a; }
            if (iou > 0.5f) zm |= (1 << a);
        }

        // target class label (argmax of one-hot, first-max)
        int lab = 0; float lbest = row[13];
        #pragma unroll
        for (int c = 1; c < kNC; ++c)
            if (row[13 + c] > lbest) { lbest = row[13 + c]; lab = c; }

        // nCorrect: uses prediction at (b, bn, gj, gi), computed immediately (order-free)
        long long base = ((((long long)b * kNA + bn) * kNH + gj) * kNW + gi) * kCH;
        float pc = pred[base + 0];
        float px = tanhf(pred[base + 1]) + 0.5f + (float)gi;
        float py = tanhf(pred[base + 2]) + 0.5f + (float)gj;
        float ph = expf(pred[base + 4]) * s_ah[bn];
        float pw = expf(pred[base + 5]) * s_aw[bn];
        float b1x1 = gx - gw, b1x2 = gx + gw, b1y1 = gy - gh, b1y2 = gy + gh;
        float b2x1 = px - pw, b2x2 = px + pw, b2y1 = py - ph, b2y2 = py + ph;
        float iw = fmaxf(fminf(b1x2, b2x2) - fmaxf(b1x1, b2x1) + 1.0f, 0.0f);
        float ih = fmaxf(fminf(b1y2, b2y2) - fmaxf(b1y1, b2y1) + 1.0f, 0.0f);
        float inter2 = iw * ih;
        float a1 = (b1x2 - b1x1 + 1.0f) * (b1y2 - b1y1 + 1.0f);
        float a2 = (b2x2 - b2x1 + 1.0f) * (b2y2 - b2y1 + 1.0f);
        float iou2 = inter2 / (a1 + a2 - inter2 + 1e-16f);
        int plab = 0; float pbest = pred[base + 6];
        #pragma unroll
        for (int c = 1; c < kNC; ++c) {
            float v = pred[base + 6 + c];
            if (v > pbest) { pbest = v; plab = c; }
        }
        int correct = valid && (iou2 > 0.5f) && (plab == lab) && (pc > 0.0f);

        s_cell[t] = gj * kNW + gi;
        s_bn[t] = bn; s_zm[t] = zm; s_valid[t] = valid;
        s_label[t] = lab; s_corr[t] = correct;
        s_tx[t] = inv_tanhf(gx - ((float)gi + 0.5f));
        s_ty[t] = inv_tanhf(gy - ((float)gj + 0.5f));
        s_tw[t] = logf(gw / s_aw[bn] + 1e-16f);
        s_th[t] = logf(gh / s_ah[bn] + 1e-16f);
    }
    __syncthreads();

    // phase 3: serial last-writer-wins replay (exact scan semantics)
    if (tid == 0) {
        int nc = 0;
        for (int t = 0; t < kMaxT; ++t) {
            if (!s_valid[t]) continue;
            int cell = s_cell[t];
            int idx = -1;
            for (int k = 0; k < nc; ++k) if (s_cl[k] == cell) { idx = k; break; }
            if (idx < 0) { idx = nc++; s_cl[idx] = cell; s_cm[idx] = 31; s_mk[idx] = 0; }
            s_cm[idx] &= ~s_zm[t];        // zero anchors with anch_iou > 0.5
            int bn = s_bn[t];
            s_cm[idx] |= (1 << bn);       // conf_mask[bn] = 1
            s_mk[idx] |= (1 << bn);       // mask[bn] = 1
            s_v[idx][bn][0] = s_tx[t]; s_v[idx][bn][1] = s_ty[t];
            s_v[idx][bn][2] = s_tw[t]; s_v[idx][bn][3] = s_th[t];
            s_vl[idx][bn] = s_label[t];
        }
        s_ncell = nc;
    }
    __syncthreads();

    // phase 4: gather pred at touched (cell,anchor) locations; accumulate corrections
    double S_excl = 0, cnt_excl = 0, nM = 0, bce = 0;
    double sx = 0, sy = 0, sw = 0, sh = 0, ce = 0, ngt = 0, ncorr = 0;
    if (tid < kMaxT) { ngt = (double)s_valid[tid]; ncorr = (double)s_corr[tid]; }

    const int nc = s_ncell;
    for (int p = tid; p < nc * kNA; p += 64) {
        int idx = p / kNA, a = p % kNA;
        int msk = (s_mk[idx] >> a) & 1;
        int cm  = (s_cm[idx] >> a) & 1;
        if (!msk && cm) continue;  // untouched wrt defaults: contributes nothing
        int cell = s_cl[idx];
        int gj = cell >> 7, gi = cell & 127;
        long long base = ((((long long)b * kNA + a) * kNH + gj) * kNW + gi) * kCH;
        float pc = pred[base];
        float sp = softplusf(pc);
        // excluded from cm_false (mask==1 || conf_mask==0)
        S_excl += (double)sp; cnt_excl += 1.0;
        if (msk) {
            nM += 1.0;
            bce += (double)(sp - pc);
            float dx = pred[base + 1] - s_v[idx][a][0];
            float dy = pred[base + 2] - s_v[idx][a][1];
            float dh = pred[base + 4] - s_v[idx][a][3];
            float dw = pred[base + 5] - s_v[idx][a][2];
            sx += (double)(dx * dx); sy += (double)(dy * dy);
            sw += (double)(dw * dw); sh += (double)(dh * dh);
            // cross-entropy: lse - logit[label]
            float m20 = pred[base + 6];
            #pragma unroll
            for (int c = 1; c < kNC; ++c) m20 = fmaxf(m20, pred[base + 6 + c]);
            float es = 0.0f;
            #pragma unroll
            for (int c = 0; c < kNC; ++c) es += expf(pred[base + 6 + c] - m20);
            float lse = m20 + logf(es);
            ce += (double)(lse - pred[base + 6 + s_vl[idx][a]]);
        }
    }

    // single-wave reductions (blockDim = 64 = 1 wave)
    S_excl = wave_sum(S_excl); cnt_excl = wave_sum(cnt_excl);
    nM = wave_sum(nM); bce = wave_sum(bce);
    sx = wave_sum(sx); sy = wave_sum(sy); sw = wave_sum(sw); sh = wave_sum(sh);
    ce = wave_sum(ce); ngt = wave_sum(ngt); ncorr = wave_sum(ncorr);
    if (tid == 0) {
        atomicAdd(&ws[2], S_excl); atomicAdd(&ws[3], cnt_excl);
        atomicAdd(&ws[4], nM);     atomicAdd(&ws[5], bce);
        atomicAdd(&ws[6], sx);     atomicAdd(&ws[7], sy);
        atomicAdd(&ws[8], sw);     atomicAdd(&ws[9], sh);
        atomicAdd(&ws[10], ce);    atomicAdd(&ws[11], ngt);
        atomicAdd(&ws[12], ncorr);
    }
}

extern "C" __global__ void yolo_finalize(const double* __restrict__ ws,
                                         float* __restrict__ out) {
    double S_all = ws[0], nProp = ws[1], S_excl = ws[2], cnt_excl = ws[3];
    double nMc = ws[4], bce = ws[5];
    double sx = ws[6], sy = ws[7], sw = ws[8], sh = ws[9], ce = ws[10];
    double nGT = ws[11], nCorr = ws[12];
    double nM = fmax(nMc, 1.0);
    double nF = fmax((double)kNTot - cnt_excl, 1.0);
    double loss_conf = 1.25 * (S_all - S_excl) / nF + bce / nM;
    double loss = (sx + sy + sw + sh) / nM + loss_conf + (ce / nM) / 16.0;
    double recall = (nGT > 0.0) ? nCorr / fmax(nGT, 1.0) : 1.0;
    double precision = (nProp > 0.0) ? nCorr / fmax(nProp, 1.0) : 1.0;
    out[0] = (float)loss;
    out[1] = (float)recall;
    out[2] = (float)precision;
}

extern "C" void kernel_launch(void* const* d_in, const int* in_sizes, int n_in,
                              void* d_out, int out_size, void* d_ws, size_t ws_size,
                              hipStream_t stream) {
    const float* pred    = (const float*)d_in[0];
    const float* target  = (const float*)d_in[1];
    const int*   tsizes  = (const int*)d_in[2];
    const float* anchors = (const float*)d_in[3];
    float* out = (float*)d_out;
    double* ws = (double*)d_ws;

    hipMemsetAsync(d_ws, 0, 13 * sizeof(double), stream);
    yolo_dense_conf<<<2048, 256, 0, stream>>>(pred, ws);
    yolo_targets<<<kNB, 64, 0, stream>>>(pred, target, tsizes, anchors, ws);
    yolo_finalize<<<1, 1, 0, stream>>>(ws, out);
}

// Round 2
// 79.455 us; speedup vs baseline: 2.0333x; 2.0333x over previous
//
#include <hip/hip_runtime.h>
#include <math.h>

#define kNB 16
#define kNA 5
#define kNH 128
#define kNW 128
#define kMaxT 50
#define kNC 20
#define kCH 26
#define kRowW 33
#define kNTot (kNB*kNA*kNH*kNW)         // 1,310,720
#define DENSE_BLOCKS 2048
#define TOT_F4 (kNTot * kCH / 4)        // 8,519,680 exact

// ws layout (doubles):
// 0 S_all  1 nProposals  2 S_excl  3 cnt_excl  4 nM  5 bce_mask
// 6 sx 7 sy 8 sw 9 sh  10 ce_sum  11 nGT  12 nCorrect

__device__ __forceinline__ float softplusf(float x) {
    return fmaxf(x, 0.0f) + log1pf(expf(-fabsf(x)));
}

__device__ __forceinline__ double wave_sum(double v) {
    #pragma unroll
    for (int off = 32; off > 0; off >>= 1) v += __shfl_down(v, off, 64);
    return v;
}

__device__ __forceinline__ float inv_tanhf(float y) {
    float yc = fminf(fmaxf(y, -1.0f + 1e-6f), 1.0f - 1e-6f);
    float v = 0.5f * logf((1.0f + yc) / (1.0f - yc));
    return (y <= -1.0f) ? -2.0f : ((y >= 1.0f) ? 2.0f : v);
}

extern "C" __global__ __launch_bounds__(256)
void yolo_main(const float* __restrict__ pred, const float* __restrict__ target,
               const int* __restrict__ tsizes, const float* __restrict__ anchors,
               double* __restrict__ ws)
{
    const int tid = threadIdx.x;

    if (blockIdx.x >= kNB) {
        // ================= dense conf stream (coalesced float4) =================
        __shared__ double s_red[8];
        float sp_sum = 0.0f;
        int prop = 0;
        const float4* __restrict__ p4 = (const float4*)pred;
        const int stride = DENSE_BLOCKS * 256;
        for (int i = (int)(blockIdx.x - kNB) * 256 + tid; i < TOT_F4; i += stride) {
            float4 v = p4[i];
            int r = (i * 4) % 26;               // conf dword iff (4i+j)%26==0
            float p = 0.0f;
            bool has = true;
            if (r == 0)       p = v.x;          // j0 = 0
            else if (r == 25) p = v.y;          // j0 = 1
            else if (r == 24) p = v.z;          // j0 = 2
            else if (r == 23) p = v.w;          // j0 = 3
            else has = false;
            if (has) { sp_sum += softplusf(p); prop += (p > 0.0f) ? 1 : 0; }
        }
        double spd = wave_sum((double)sp_sum);
        double prd = wave_sum((double)prop);
        int wid = tid >> 6;
        if ((tid & 63) == 0) { s_red[wid] = spd; s_red[4 + wid] = prd; }
        __syncthreads();
        if (tid == 0) {
            atomicAdd(&ws[0], s_red[0] + s_red[1] + s_red[2] + s_red[3]);
            atomicAdd(&ws[1], s_red[4] + s_red[5] + s_red[6] + s_red[7]);
        }
        return;
    }

    // ================= sparse targets part (one block per batch) =================
    const int b = blockIdx.x;
    __shared__ float s_t[kMaxT][kRowW];
    __shared__ float s_aw[kNA], s_ah[kNA];
    __shared__ int s_cell[kMaxT], s_bn[kMaxT], s_zm[kMaxT], s_valid[kMaxT];
    __shared__ int s_label[kMaxT];
    __shared__ float s_tx[kMaxT], s_ty[kMaxT], s_tw[kMaxT], s_th[kMaxT];

    for (int i = tid; i < kMaxT * kRowW; i += 256)
        ((float*)s_t)[i] = target[(long long)b * kMaxT * kRowW + i];
    if (tid < kNA) {
        s_aw[tid] = anchors[tid * 2 + 0] / 8.0f;
        s_ah[tid] = anchors[tid * 2 + 1] / 8.0f;
    }
    __syncthreads();

    const int tsz = tsizes[b];
    double ngt = 0.0, ncorr = 0.0;
    int myCell = -1;

    // ---- phase 2: per-target independent compute (50 lanes in parallel) ----
    if (tid < kMaxT) {
        const float* row = s_t[tid];
        float gx = row[0] / 8.0f, gy = row[1] / 8.0f;
        float gh = row[3] / 8.0f, gw = row[4] / 8.0f;
        int valid = (tid < tsz) && (gw != 0.0f) && (gh != 0.0f);
        int gi = min(max((int)gx, 0), kNW - 1);
        int gj = min(max((int)gy, 0), kNH - 1);

        float best = -1.0f; int bn = 0; int zm = 0;
        #pragma unroll
        for (int a = 0; a < kNA; ++a) {
            float aw = s_aw[a], ah = s_ah[a];
            float inter = fmaxf(fminf(gw, aw) + 1.0f, 0.0f) * fmaxf(fminf(gh, ah) + 1.0f, 0.0f);
            float iou = inter / ((gw + 1.0f) * (gh + 1.0f) + (aw + 1.0f) * (ah + 1.0f) - inter + 1e-16f);
            if (iou > best) { best = iou; bn = a; }
            if (iou > 0.5f) zm |= (1 << a);
        }

        int lab = 0; float lbest = row[13];
        #pragma unroll
        for (int c = 1; c < kNC; ++c)
            if (row[13 + c] > lbest) { lbest = row[13 + c]; lab = c; }

        // nCorrect (order-free, uses pred at (b,bn,gj,gi))
        long long base = ((((long long)b * kNA + bn) * kNH + gj) * kNW + gi) * kCH;
        float pc = pred[base + 0];
        float px = tanhf(pred[base + 1]) + 0.5f + (float)gi;
        float py = tanhf(pred[base + 2]) + 0.5f + (float)gj;
        float ph = expf(pred[base + 4]) * s_ah[bn];
        float pw = expf(pred[base + 5]) * s_aw[bn];
        float b1x1 = gx - gw, b1x2 = gx + gw, b1y1 = gy - gh, b1y2 = gy + gh;
        float b2x1 = px - pw, b2x2 = px + pw, b2y1 = py - ph, b2y2 = py + ph;
        float iw = fmaxf(fminf(b1x2, b2x2) - fmaxf(b1x1, b2x1) + 1.0f, 0.0f);
        float ih = fmaxf(fminf(b1y2, b2y2) - fmaxf(b1y1, b2y1) + 1.0f, 0.0f);
        float inter2 = iw * ih;
        float a1 = (b1x2 - b1x1 + 1.0f) * (b1y2 - b1y1 + 1.0f);
        float a2 = (b2x2 - b2x1 + 1.0f) * (b2y2 - b2y1 + 1.0f);
        float iou2 = inter2 / (a1 + a2 - inter2 + 1e-16f);
        int plab = 0; float pbest = pred[base + 6];
        #pragma unroll
        for (int c = 1; c < kNC; ++c) {
            float v = pred[base + 6 + c];
            if (v > pbest) { pbest = v; plab = c; }
        }
        int correct = valid && (iou2 > 0.5f) && (plab == lab) && (pc > 0.0f);

        myCell = gj * kNW + gi;
        s_cell[tid] = myCell; s_bn[tid] = bn; s_zm[tid] = zm; s_valid[tid] = valid;
        s_label[tid] = lab;
        s_tx[tid] = inv_tanhf(gx - ((float)gi + 0.5f));
        s_ty[tid] = inv_tanhf(gy - ((float)gj + 0.5f));
        s_tw[tid] = logf(gw / s_aw[bn] + 1e-16f);
        s_th[tid] = logf(gh / s_ah[bn] + 1e-16f);
        ngt = (double)valid; ncorr = (double)correct;
    }
    __syncthreads();

    // ---- phase 3: lane-parallel last-writer-wins resolution ----
    double S_excl = 0, cnt_excl = 0, nM = 0, bce = 0;
    double sx = 0, sy = 0, sw_ = 0, sh_ = 0, ce = 0;

    if (tid < kMaxT) {
        int lastTouch[kNA], lastSet[kNA], lastCm[kNA];
        #pragma unroll
        for (int a = 0; a < kNA; ++a) { lastTouch[a] = -1; lastSet[a] = -1; lastCm[a] = 0; }

        for (int tp = 0; tp < kMaxT; ++tp) {           // LDS broadcast scan
            if (!s_valid[tp] || s_cell[tp] != myCell) continue;
            int bnp = s_bn[tp], zmp = s_zm[tp];
            #pragma unroll
            for (int a = 0; a < kNA; ++a) {
                bool setr = (bnp == a);
                if (setr || ((zmp >> a) & 1)) { lastTouch[a] = tp; lastCm[a] = setr ? 1 : 0; }
                if (setr) lastSet[a] = tp;
            }
        }

        int gj = myCell >> 7, gi = myCell & 127;
        #pragma unroll
        for (int a = 0; a < kNA; ++a) {
            if (lastTouch[a] != tid) continue;          // unique owner per (cell,a)
            bool msk = lastSet[a] >= 0;                 // final mask
            bool cmf = lastCm[a] != 0;                  // final conf_mask
            if (!msk && cmf) continue;                  // same as default: no correction
            long long base = ((((long long)b * kNA + a) * kNH + gj) * kNW + gi) * kCH;
            float pc = pred[base];
            float sp = softplusf(pc);
            S_excl += (double)sp; cnt_excl += 1.0;      // excluded from cm_false
            if (msk) {
                int ts = lastSet[a];
                nM += 1.0; bce += (double)(sp - pc);
                float dx = pred[base + 1] - s_tx[ts];
                float dy = pred[base + 2] - s_ty[ts];
                float dh = pred[base + 4] - s_th[ts];
                float dw = pred[base + 5] - s_tw[ts];
                sx += (double)(dx * dx); sy += (double)(dy * dy);
                sw_ += (double)(dw * dw); sh_ += (double)(dh * dh);
                float m20 = pred[base + 6];
                #pragma unroll
                for (int c = 1; c < kNC; ++c) m20 = fmaxf(m20, pred[base + 6 + c]);
                float es = 0.0f;
                #pragma unroll
                for (int c = 0; c < kNC; ++c) es += expf(pred[base + 6 + c] - m20);
                ce += (double)(m20 + logf(es) - pred[base + 6 + s_label[ts]]);
            }
        }
    }

    if (tid < 64) {  // single-wave reduction
        S_excl = wave_sum(S_excl); cnt_excl = wave_sum(cnt_excl);
        nM = wave_sum(nM); bce = wave_sum(bce);
        sx = wave_sum(sx); sy = wave_sum(sy); sw_ = wave_sum(sw_); sh_ = wave_sum(sh_);
        ce = wave_sum(ce); ngt = wave_sum(ngt); ncorr = wave_sum(ncorr);
        if (tid == 0) {
            atomicAdd(&ws[2], S_excl); atomicAdd(&ws[3], cnt_excl);
            atomicAdd(&ws[4], nM);     atomicAdd(&ws[5], bce);
            atomicAdd(&ws[6], sx);     atomicAdd(&ws[7], sy);
            atomicAdd(&ws[8], sw_);    atomicAdd(&ws[9], sh_);
            atomicAdd(&ws[10], ce);    atomicAdd(&ws[11], ngt);
            atomicAdd(&ws[12], ncorr);
        }
    }
}

extern "C" __global__ void yolo_finalize(const double* __restrict__ ws,
                                         float* __restrict__ out) {
    double S_all = ws[0], nProp = ws[1], S_excl = ws[2], cnt_excl = ws[3];
    double nMc = ws[4], bce = ws[5];
    double sx = ws[6], sy = ws[7], sw = ws[8], sh = ws[9], ce = ws[10];
    double nGT = ws[11], nCorr = ws[12];
    double nM = fmax(nMc, 1.0);
    double nF = fmax((double)kNTot - cnt_excl, 1.0);
    double loss_conf = 1.25 * (S_all - S_excl) / nF + bce / nM;
    double loss = (sx + sy + sw + sh) / nM + loss_conf + (ce / nM) / 16.0;
    double recall = (nGT > 0.0) ? nCorr / fmax(nGT, 1.0) : 1.0;
    double precision = (nProp > 0.0) ? nCorr / fmax(nProp, 1.0) : 1.0;
    out[0] = (float)loss;
    out[1] = (float)recall;
    out[2] = (float)precision;
}

extern "C" void kernel_launch(void* const* d_in, const int* in_sizes, int n_in,
                              void* d_out, int out_size, void* d_ws, size_t ws_size,
                              hipStream_t stream) {
    const float* pred    = (const float*)d_in[0];
    const float* target  = (const float*)d_in[1];
    const int*   tsizes  = (const int*)d_in[2];
    const float* anchors = (const float*)d_in[3];
    float* out = (float*)d_out;
    double* ws = (double*)d_ws;

    hipMemsetAsync(d_ws, 0, 13 * sizeof(double), stream);
    yolo_main<<<DENSE_BLOCKS + kNB, 256, 0, stream>>>(pred, target, tsizes, anchors, ws);
    yolo_finalize<<<1, 1, 0, stream>>>(ws, out);
}